// Round 1
// baseline (17397.202 us; speedup 1.0000x reference)
//
#include <hip/hip_runtime.h>
#include <math.h>

// GRU sublayer: B=64, T=512, DI=1024, DH=1024.
// outputs (B,T,DH) f32 then H_last (B,DH) f32 in d_out.
//
// Phase 1: Zx = X@Wz_x + bz -> d_out (f32, overwritten by H later)
//          Rx,Nx -> ws (fp16)
// Scan:    per step t: S1: Z=sig(zx+H@Wzh), R=sig(rx+H@Wrh), RH=R*H
//                      S2: Ht=tanh(nx+RH@Wnh), H=(1-Z)H+Z*Ht
// All matmuls fp16 MFMA 16x16x32, f32 accumulate. H kept f32.

typedef _Float16 h8 __attribute__((ext_vector_type(8)));
typedef float f4 __attribute__((ext_vector_type(4)));

#define NB 64
#define NT 512
#define ND 1024
#define NROWS (NB * NT)   // 32768

static __device__ __forceinline__ f4 mfma16(h8 a, h8 b, f4 c) {
  return __builtin_amdgcn_mfma_f32_16x16x32_f16(a, b, c, 0, 0, 0);
}

static __device__ __forceinline__ h8 cvt8(float4 a, float4 b) {
  h8 r;
  r[0] = (_Float16)a.x; r[1] = (_Float16)a.y; r[2] = (_Float16)a.z; r[3] = (_Float16)a.w;
  r[4] = (_Float16)b.x; r[5] = (_Float16)b.y; r[6] = (_Float16)b.z; r[7] = (_Float16)b.w;
  return r;
}

// ---------------------------------------------------------------------------
// Transpose + fp16-convert the 6 weight halves:
// z slab index: 0=Wz_x 1=Wz_h 2=Wr_x 3=Wr_h 4=Wn_x 5=Wn_h
// WT[slab][n][k] = (fp16) W[khalf*1024 + k][n]
// ---------------------------------------------------------------------------
__global__ void k_transpose(const float* __restrict__ Wz, const float* __restrict__ Wr,
                            const float* __restrict__ Wn, _Float16* __restrict__ WT) {
  __shared__ float tile[32][33];
  const int zid = blockIdx.z;
  const float* W = (zid < 2) ? Wz : (zid < 4) ? Wr : Wn;
  const int rowoff = (zid & 1) * ND;
  const int k0 = blockIdx.x * 32;
  const int n0 = blockIdx.y * 32;
  const int tx = threadIdx.x, ty = threadIdx.y;   // 32 x 8
#pragma unroll
  for (int i = 0; i < 32; i += 8)
    tile[ty + i][tx] = W[(size_t)(rowoff + k0 + ty + i) * ND + n0 + tx];
  __syncthreads();
  _Float16* out = WT + (size_t)zid * ND * ND;
#pragma unroll
  for (int i = 0; i < 32; i += 8)
    out[(size_t)(n0 + ty + i) * ND + k0 + tx] = (_Float16)tile[tx][ty + i];
}

// H_run = h0 (f32), Hh = fp16(h0)
__global__ void k_init(const float* __restrict__ h0, float* __restrict__ Hrun,
                       _Float16* __restrict__ Hh) {
  int i = blockIdx.x * 256 + threadIdx.x;   // grid 256 blocks -> 65536
  float v = h0[i];
  Hrun[i] = v;
  Hh[i] = (_Float16)v;
}

// ---------------------------------------------------------------------------
// Phase-1 GEMM: all 3 gates per block. Tile 64x64, BK=64, 4 waves (16 rows ea).
// A = X (f32 -> fp16 in LDS). B = WxT slabs (fp16, [n][k] contiguous in k).
// ---------------------------------------------------------------------------
__launch_bounds__(256)
__global__ void k_xproj(const float* __restrict__ X, const _Float16* __restrict__ WT,
                        const float* __restrict__ bz, const float* __restrict__ br,
                        const float* __restrict__ bn, float* __restrict__ Zx,
                        _Float16* __restrict__ Rxh, _Float16* __restrict__ Nxh) {
  __shared__ _Float16 At[64][72];
  __shared__ _Float16 Bt[3][64][72];
  const int m0 = blockIdx.x * 64, n0 = blockIdx.y * 64;
  const int tid = threadIdx.x;
  const int w = tid >> 6, l = tid & 63, lr = l & 15, lk = l >> 4;

  const _Float16* Wx0 = WT;
  const _Float16* Wx1 = WT + (size_t)2 * ND * ND;
  const _Float16* Wx2 = WT + (size_t)4 * ND * ND;

  f4 acc[3][4];
#pragma unroll
  for (int g = 0; g < 3; ++g)
#pragma unroll
    for (int cb = 0; cb < 4; ++cb) acc[g][cb] = (f4){0.f, 0.f, 0.f, 0.f};

  const int sm = tid >> 2;          // 0..63 (row for staging)
  const int sk = (tid & 3) * 16;    // k offset within BK=64

  for (int k0 = 0; k0 < ND; k0 += 64) {
    // stage A: 64 rows x 64 k, f32 -> fp16
    {
      const float4* pa = reinterpret_cast<const float4*>(X + (size_t)(m0 + sm) * ND + k0 + sk);
      float4 a0 = pa[0], a1 = pa[1], a2 = pa[2], a3 = pa[3];
      *reinterpret_cast<h8*>(&At[sm][sk]) = cvt8(a0, a1);
      *reinterpret_cast<h8*>(&At[sm][sk + 8]) = cvt8(a2, a3);
    }
    // stage B (3 gates): already fp16 + transposed in global
    {
      const _Float16* b0 = Wx0 + (size_t)(n0 + sm) * ND + k0 + sk;
      const _Float16* b1 = Wx1 + (size_t)(n0 + sm) * ND + k0 + sk;
      const _Float16* b2 = Wx2 + (size_t)(n0 + sm) * ND + k0 + sk;
      *reinterpret_cast<h8*>(&Bt[0][sm][sk]) = *reinterpret_cast<const h8*>(b0);
      *reinterpret_cast<h8*>(&Bt[0][sm][sk + 8]) = *reinterpret_cast<const h8*>(b0 + 8);
      *reinterpret_cast<h8*>(&Bt[1][sm][sk]) = *reinterpret_cast<const h8*>(b1);
      *reinterpret_cast<h8*>(&Bt[1][sm][sk + 8]) = *reinterpret_cast<const h8*>(b1 + 8);
      *reinterpret_cast<h8*>(&Bt[2][sm][sk]) = *reinterpret_cast<const h8*>(b2);
      *reinterpret_cast<h8*>(&Bt[2][sm][sk + 8]) = *reinterpret_cast<const h8*>(b2 + 8);
    }
    __syncthreads();
#pragma unroll
    for (int kc = 0; kc < 2; ++kc) {
      h8 af = *reinterpret_cast<const h8*>(&At[w * 16 + lr][kc * 32 + lk * 8]);
#pragma unroll
      for (int g = 0; g < 3; ++g) {
#pragma unroll
        for (int cb = 0; cb < 4; ++cb) {
          h8 bf = *reinterpret_cast<const h8*>(&Bt[g][cb * 16 + lr][kc * 32 + lk * 8]);
          acc[g][cb] = mfma16(af, bf, acc[g][cb]);
        }
      }
    }
    __syncthreads();
  }

  // epilogue: D row = w*16 + lk*4 + j, col = n0 + cb*16 + lr
#pragma unroll
  for (int cb = 0; cb < 4; ++cb) {
    int n = n0 + cb * 16 + lr;
    float bzv = bz[n], brv = br[n], bnv = bn[n];
#pragma unroll
    for (int j = 0; j < 4; ++j) {
      int m = m0 + w * 16 + lk * 4 + j;
      size_t idx = (size_t)m * ND + n;
      Zx[idx] = acc[0][cb][j] + bzv;
      Rxh[idx] = (_Float16)(acc[1][cb][j] + brv);
      Nxh[idx] = (_Float16)(acc[2][cb][j] + bnv);
    }
  }
}

// ---------------------------------------------------------------------------
// Scan step phase A: gate 0 -> Z = sigmoid(zx + H@Wzh) -> Zbuf
//                    gate 1 -> R = sigmoid(rx + H@Wrh), RHh = fp16(R*H)
// grid (32 col-tiles of 32, 2 gates), 256 threads (4 waves x 16 rows).
// ---------------------------------------------------------------------------
__launch_bounds__(256)
__global__ void k_step1(int t, const _Float16* __restrict__ Hh,
                        const _Float16* __restrict__ WhTz, const _Float16* __restrict__ WhTr,
                        const float* __restrict__ Zx, const _Float16* __restrict__ Rxh,
                        const float* __restrict__ Hrun, float* __restrict__ Zbuf,
                        _Float16* __restrict__ RHh) {
  const int n0 = blockIdx.x * 32;
  const int gate = blockIdx.y;
  const int tid = threadIdx.x;
  const int w = tid >> 6, l = tid & 63, lr = l & 15, lk = l >> 4;
  const _Float16* __restrict__ WT = gate ? WhTr : WhTz;

  f4 acc0 = (f4){0.f, 0.f, 0.f, 0.f}, acc1 = acc0;
  const _Float16* ap = Hh + (size_t)(w * 16 + lr) * ND + lk * 8;
  const _Float16* bp0 = WT + (size_t)(n0 + lr) * ND + lk * 8;
  const _Float16* bp1 = WT + (size_t)(n0 + 16 + lr) * ND + lk * 8;
#pragma unroll 4
  for (int k0 = 0; k0 < ND; k0 += 32) {
    h8 af = *reinterpret_cast<const h8*>(ap + k0);
    h8 b0 = *reinterpret_cast<const h8*>(bp0 + k0);
    h8 b1 = *reinterpret_cast<const h8*>(bp1 + k0);
    acc0 = mfma16(af, b0, acc0);
    acc1 = mfma16(af, b1, acc1);
  }
  f4 accs[2] = {acc0, acc1};
#pragma unroll
  for (int cb = 0; cb < 2; ++cb) {
    int n = n0 + cb * 16 + lr;
#pragma unroll
    for (int j = 0; j < 4; ++j) {
      int b = w * 16 + lk * 4 + j;
      size_t mi = ((size_t)b * NT + (size_t)t) * ND + n;
      size_t hi = (size_t)b * ND + n;
      if (gate == 0) {
        float v = Zx[mi] + accs[cb][j];
        Zbuf[hi] = 1.0f / (1.0f + __expf(-v));
      } else {
        float v = (float)Rxh[mi] + accs[cb][j];
        float r = 1.0f / (1.0f + __expf(-v));
        RHh[hi] = (_Float16)(r * Hrun[hi]);
      }
    }
  }
}

// ---------------------------------------------------------------------------
// Scan step phase B: Gn = RH@Wnh, Ht = tanh(nx+Gn), H = (1-Z)H + Z*Ht
// grid (32 col-tiles of 32), 256 threads.
// ---------------------------------------------------------------------------
__launch_bounds__(256)
__global__ void k_step2(int t, const _Float16* __restrict__ RHh,
                        const _Float16* __restrict__ WhTn, const _Float16* __restrict__ Nxh,
                        const float* __restrict__ Zbuf, float* __restrict__ Hrun,
                        _Float16* __restrict__ Hh, float* __restrict__ Out) {
  const int n0 = blockIdx.x * 32;
  const int tid = threadIdx.x;
  const int w = tid >> 6, l = tid & 63, lr = l & 15, lk = l >> 4;

  f4 acc0 = (f4){0.f, 0.f, 0.f, 0.f}, acc1 = acc0;
  const _Float16* ap = RHh + (size_t)(w * 16 + lr) * ND + lk * 8;
  const _Float16* bp0 = WhTn + (size_t)(n0 + lr) * ND + lk * 8;
  const _Float16* bp1 = WhTn + (size_t)(n0 + 16 + lr) * ND + lk * 8;
#pragma unroll 4
  for (int k0 = 0; k0 < ND; k0 += 32) {
    h8 af = *reinterpret_cast<const h8*>(ap + k0);
    h8 b0 = *reinterpret_cast<const h8*>(bp0 + k0);
    h8 b1 = *reinterpret_cast<const h8*>(bp1 + k0);
    acc0 = mfma16(af, b0, acc0);
    acc1 = mfma16(af, b1, acc1);
  }
  f4 accs[2] = {acc0, acc1};
#pragma unroll
  for (int cb = 0; cb < 2; ++cb) {
    int n = n0 + cb * 16 + lr;
#pragma unroll
    for (int j = 0; j < 4; ++j) {
      int b = w * 16 + lk * 4 + j;
      size_t mi = ((size_t)b * NT + (size_t)t) * ND + n;
      size_t hi = (size_t)b * ND + n;
      float v = (float)Nxh[mi] + accs[cb][j];
      float e = __expf(2.0f * v);
      float ht = (e - 1.0f) / (e + 1.0f);   // tanh; |v| <~ 10 here, no overflow
      float z = Zbuf[hi];
      float ho = Hrun[hi];
      float hn = ho + z * (ht - ho);
      Hrun[hi] = hn;
      Hh[hi] = (_Float16)hn;
      Out[mi] = hn;
    }
  }
}

// ---------------------------------------------------------------------------
extern "C" void kernel_launch(void* const* d_in, const int* in_sizes, int n_in,
                              void* d_out, int out_size, void* d_ws, size_t ws_size,
                              hipStream_t stream) {
  const float* X = (const float*)d_in[0];
  const float* h0 = (const float*)d_in[1];
  const float* Wz = (const float*)d_in[2];
  const float* bz = (const float*)d_in[3];
  const float* Wr = (const float*)d_in[4];
  const float* br = (const float*)d_in[5];
  const float* Wn = (const float*)d_in[6];
  const float* bn = (const float*)d_in[7];

  float* out = (float*)d_out;
  float* Hrun = out + (size_t)NROWS * ND;   // H_last region doubles as running H

  // ws layout (halves):
  _Float16* wsh = (_Float16*)d_ws;
  _Float16* Rxh = wsh;                                  // 32768*1024
  _Float16* Nxh = Rxh + (size_t)NROWS * ND;             // 32768*1024
  _Float16* WT = Nxh + (size_t)NROWS * ND;              // 6 * 1024*1024
  _Float16* Hh = WT + (size_t)6 * ND * ND;              // 64*1024
  _Float16* RHh = Hh + (size_t)NB * ND;                 // 64*1024
  float* Zbuf = (float*)(RHh + (size_t)NB * ND);        // 64*1024 f32

  const _Float16* WhTz = WT + (size_t)1 * ND * ND;
  const _Float16* WhTr = WT + (size_t)3 * ND * ND;
  const _Float16* WhTn = WT + (size_t)5 * ND * ND;

  k_transpose<<<dim3(32, 32, 6), dim3(32, 8), 0, stream>>>(Wz, Wr, Wn, WT);
  k_init<<<dim3(256), dim3(256), 0, stream>>>(h0, Hrun, Hh);
  k_xproj<<<dim3(NROWS / 64, ND / 64), dim3(256), 0, stream>>>(X, WT, bz, br, bn, out, Rxh, Nxh);

  for (int t = 0; t < NT; ++t) {
    k_step1<<<dim3(32, 2), dim3(256), 0, stream>>>(t, Hh, WhTz, WhTr, out, Rxh, Hrun, Zbuf, RHh);
    k_step2<<<dim3(32), dim3(256), 0, stream>>>(t, RHh, WhTn, Nxh, Zbuf, Hrun, Hh, out);
  }
}